// Round 3
// baseline (264.763 us; speedup 1.0000x reference)
//
#include <hip/hip_runtime.h>
#include <math.h>

#define C_DIM  64
#define CQ     8
#define BATCH  2
#define NVOX   8000
#define MT     32            // queries per block
#define KT     64            // keys per tile
#define NTILES 125           // 8000/64
#define NSUP   32            // supers of 4 tiles (31 full + tail)
#define QTILES 250           // 8000/32
#define PSTRIDE 72           // pT row stride in u16 (144B: balanced banks)

typedef float  f32x16 __attribute__((ext_vector_type(16)));
typedef __bf16 bf16x8 __attribute__((ext_vector_type(8)));
typedef unsigned short u16x8 __attribute__((ext_vector_type(8)));

__device__ __forceinline__ unsigned short f2bf(float f) {
    return __builtin_bit_cast(unsigned short, (__bf16)f);
}

// ---------------------------------------------------------------------------
// Kernel 1: projections. W staged in LDS (broadcast reads, no SMEM re-fetch).
// 250 blocks x 256 thr; wave w computes output-slice sub=w for 64 voxels.
// Outputs: qws [vox][hi8|lo8] bf16 (split-precision), kws [vox][8] bf16,
//          vws planar [b][c][n] bf16.
// ---------------------------------------------------------------------------
__global__ __launch_bounds__(256) void qkv_kernel(
    const float* __restrict__ x,
    const float* __restrict__ wq, const float* __restrict__ bq,
    const float* __restrict__ wk, const float* __restrict__ bk,
    const float* __restrict__ wv, const float* __restrict__ bv,
    unsigned short* __restrict__ qws, unsigned short* __restrict__ kws,
    unsigned short* __restrict__ vws)
{
    __shared__ __align__(16) float Wt[64][80];   // [c][out]: 0-7 q, 8-15 k, 16-79 v
    const int t = threadIdx.x;
    for (int idx = t; idx < 80 * 64; idx += 256) {
        int o = idx >> 6, c = idx & 63;
        float w;
        if (o < 8)       w = wq[o * 64 + c];
        else if (o < 16) w = wk[(o - 8) * 64 + c];
        else             w = wv[(o - 16) * 64 + c];
        Wt[c][o] = w;
    }
    __syncthreads();

    const int lane = t & 63;
    const int sub  = t >> 6;                       // 0..3: outputs sub*20..+19
    const int vox  = blockIdx.x * 64 + lane;       // 0..15999
    const int b    = vox >= NVOX;
    const int n    = vox - b * NVOX;
    const float* xp = x + (size_t)b * C_DIM * NVOX + n;
    const int o0 = sub * 20;

    float acc[20];
#pragma unroll
    for (int j = 0; j < 20; ++j) {
        int o = o0 + j;
        acc[j] = (o < 8) ? bq[o] : (o < 16 ? bk[o - 8] : bv[o - 16]);
    }
#pragma unroll 4
    for (int c = 0; c < 64; ++c) {
        float xc = xp[(size_t)c * NVOX];           // coalesced; L1-hit for subs 1-3
        const float* wr = &Wt[c][o0];
#pragma unroll
        for (int j = 0; j < 20; ++j)
            acc[j] = fmaf(wr[j], xc, acc[j]);
    }

    if (sub == 0) {
        unsigned short hi[8], lo[8], kk[8];
#pragma unroll
        for (int j = 0; j < 8; ++j) {
            float q = acc[j];
            __bf16 hq = (__bf16)q;
            hi[j] = __builtin_bit_cast(unsigned short, hq);
            lo[j] = f2bf(q - (float)hq);
            kk[j] = f2bf(acc[8 + j]);
        }
        uint4* qo = (uint4*)(qws + (size_t)vox * 16);
        qo[0] = *(uint4*)hi;
        qo[1] = *(uint4*)lo;
        *(uint4*)(kws + (size_t)vox * 8) = *(uint4*)kk;
#pragma unroll
        for (int j = 16; j < 20; ++j) {
            int c = j - 16;
            vws[((size_t)b * 64 + c) * NVOX + n] = f2bf(acc[j]);
        }
    } else {
#pragma unroll
        for (int j = 0; j < 20; ++j) {
            int c = o0 + j - 16;
            vws[((size_t)b * 64 + c) * NVOX + n] = f2bf(acc[j]);
        }
    }
}

// ---------------------------------------------------------------------------
// Kernel 2: flash attention, wave-split over key-tiles.
//   500 blocks x 256 thr. Wave w owns tiles T = 4S+w (private m,l,acc,pT).
//   Per super (4 tiles): stage V for all 4 tiles (2 barriers), then each wave
//   computes its tile with NO barriers: QK 2 MFMA -> reg softmax (1 shfl) ->
//   pT round-trip -> PV 8 MFMA. Flash-decode merge at end.
// ---------------------------------------------------------------------------
__global__ __launch_bounds__(256, 2) void attn_kernel(
    const unsigned short* __restrict__ qws, const unsigned short* __restrict__ kws,
    const unsigned short* __restrict__ vws, const float* __restrict__ x,
    const float* __restrict__ gamma, float* __restrict__ out)
{
    __shared__ __align__(16) unsigned char smem[32768 + 18432 + 2048];
    unsigned short* v16 = (unsigned short*)smem;              // [tile4][kb8][c64][8]
    unsigned short* pT  = (unsigned short*)(smem + 32768);    // [wave][32][72]
    float* m_sh = (float*)(smem + 32768 + 18432);             // [4][64]
    float* l_sh = m_sh + 256;                                 // [4][64]
    float* mergeF = (float*)smem;                             // [wave][chalf][64][16]

    const int blk  = blockIdx.x;
    const int b    = blk / QTILES;
    const int m0   = (blk % QTILES) * MT;
    const int t    = threadIdx.x;
    const int lane = t & 63;
    const int w    = t >> 6;
    const int l31  = lane & 31;
    const int h    = lane >> 5;

    // persistent Q B-frag: lane col = query l31; h=0 lanes carry qhi (kdims 0-7),
    // h=1 carry qlo (kdims 8-15). K A-frag is duplicated across h -> (qhi+qlo)*k.
    const bf16x8 qf = __builtin_bit_cast(bf16x8,
        *(const u16x8*)(qws + (size_t)(b * NVOX + m0 + l31) * 16 + h * 8));

    // V staging mapping: thread -> channel sc, key-group sg (64 keys = 8 chunks)
    const int sc = t >> 2;
    const int sg = t & 3;
    const unsigned short* vsrc = vws + ((size_t)b * C_DIM + sc) * NVOX;
    const unsigned short* ksrc = kws + (size_t)b * NVOX * 8;

    float m_run = -1e30f, l_run = 0.0f;
    f32x16 acc0, acc1, zro;
#pragma unroll
    for (int r = 0; r < 16; ++r) { acc0[r] = 0.0f; acc1[r] = 0.0f; zro[r] = 0.0f; }

    uint4 vpre[8];
#pragma unroll
    for (int j8 = 0; j8 < 8; ++j8) {
        int gk = sg * 64 + j8 * 8;
        if (gk > NVOX - 8) gk = NVOX - 8;
        vpre[j8] = *(const uint4*)(vsrc + gk);
    }

    for (int S = 0; S < NSUP; ++S) {
        __syncthreads();                      // prev super's compute done
#pragma unroll
        for (int j8 = 0; j8 < 8; ++j8)
            *(uint4*)(v16 + ((size_t)((sg * 8 + j8) * 64 + sc)) * 8) = vpre[j8];
        __syncthreads();                      // V staged

        if (S + 1 < NSUP) {                   // prefetch next super
#pragma unroll
            for (int j8 = 0; j8 < 8; ++j8) {
                int gk = (S + 1) * 256 + sg * 64 + j8 * 8;
                if (gk > NVOX - 8) gk = NVOX - 8;
                vpre[j8] = *(const uint4*)(vsrc + gk);
            }
        }

        const int T = 4 * S + w;
        if (T < NTILES) {
            const int n0 = T * KT;
            // K A-frags (16B per lane, dup across h)
            bf16x8 kf0 = __builtin_bit_cast(bf16x8,
                *(const u16x8*)(ksrc + (size_t)(n0 + l31) * 8));
            bf16x8 kf1 = __builtin_bit_cast(bf16x8,
                *(const u16x8*)(ksrc + (size_t)(n0 + 32 + l31) * 8));

            // E C-layout: col = query l31, rows = keys (reg&3)+8*(reg>>2)+4h (+32 for E1)
            f32x16 E0 = __builtin_amdgcn_mfma_f32_32x32x16_bf16(kf0, qf, zro, 0, 0, 0);
            f32x16 E1 = __builtin_amdgcn_mfma_f32_32x32x16_bf16(kf1, qf, zro, 0, 0, 0);

            // online softmax: reduce 32 regs + one shfl over the h-pair
            float tm = E0[0];
#pragma unroll
            for (int r = 1; r < 16; ++r) tm = fmaxf(tm, E0[r]);
#pragma unroll
            for (int r = 0; r < 16; ++r) tm = fmaxf(tm, E1[r]);
            tm = fmaxf(tm, __shfl_xor(tm, 32, 64));
            const float mnew  = fmaxf(m_run, tm);
            const float alpha = __expf(m_run - mnew);
            float p[32];
            float s = 0.0f;
#pragma unroll
            for (int r = 0; r < 16; ++r) { p[r]      = __expf(E0[r] - mnew); s += p[r]; }
#pragma unroll
            for (int r = 0; r < 16; ++r) { p[16 + r] = __expf(E1[r] - mnew); s += p[16 + r]; }
            s += __shfl_xor(s, 32, 64);
            m_run = mnew;
            l_run = l_run * alpha + s;

            // write P to wave-private pT in [q][key] layout (C-rows are key-consecutive by 4)
            unsigned short* prow = pT + (size_t)(w * MT + l31) * PSTRIDE;
#pragma unroll
            for (int a = 0; a < 2; ++a)
#pragma unroll
                for (int g4 = 0; g4 < 4; ++g4) {
                    ushort4 pk;
                    pk.x = f2bf(p[a * 16 + 4 * g4 + 0]);
                    pk.y = f2bf(p[a * 16 + 4 * g4 + 1]);
                    pk.z = f2bf(p[a * 16 + 4 * g4 + 2]);
                    pk.w = f2bf(p[a * 16 + 4 * g4 + 3]);
                    *(ushort4*)(prow + a * 32 + g4 * 8 + 4 * h) = pk;
                }

            // rescale acc (cols = this lane's query -> scalar alpha)
#pragma unroll
            for (int r = 0; r < 16; ++r) { acc0[r] *= alpha; acc1[r] *= alpha; }

            // PV: A = V frags from LDS, B = P frags from pT
#pragma unroll
            for (int s2 = 0; s2 < 4; ++s2) {
                bf16x8 pf = __builtin_bit_cast(bf16x8,
                    *(const u16x8*)(prow + s2 * 16 + h * 8));
                const int kb = 2 * s2 + h;
                bf16x8 va0 = __builtin_bit_cast(bf16x8,
                    *(const u16x8*)(v16 + (size_t)((w * 8 + kb) * 64 + l31) * 8));
                bf16x8 va1 = __builtin_bit_cast(bf16x8,
                    *(const u16x8*)(v16 + (size_t)((w * 8 + kb) * 64 + 32 + l31) * 8));
                acc0 = __builtin_amdgcn_mfma_f32_32x32x16_bf16(va0, pf, acc0, 0, 0, 0);
                acc1 = __builtin_amdgcn_mfma_f32_32x32x16_bf16(va1, pf, acc1, 0, 0, 0);
            }
        }
    }

    // ---- flash-decode merge across the 4 waves ----
    m_sh[w * 64 + lane] = m_run;
    l_sh[w * 64 + lane] = l_run;
    __syncthreads();                          // all compute done; v16 can be aliased
#pragma unroll
    for (int r4 = 0; r4 < 4; ++r4) {
        float4 a0 = make_float4(acc0[4*r4+0], acc0[4*r4+1], acc0[4*r4+2], acc0[4*r4+3]);
        float4 a1 = make_float4(acc1[4*r4+0], acc1[4*r4+1], acc1[4*r4+2], acc1[4*r4+3]);
        *(float4*)&mergeF[((size_t)(w * 2 + 0) * 64 + lane) * 16 + 4 * r4] = a0;
        *(float4*)&mergeF[((size_t)(w * 2 + 1) * 64 + lane) * 16 + 4 * r4] = a1;
    }
    __syncthreads();

    if (w < 2) {
        const int chalf = w;
        float mstar = m_sh[lane];
#pragma unroll
        for (int ww = 1; ww < 4; ++ww) mstar = fmaxf(mstar, m_sh[ww * 64 + lane]);
        float lstar = 0.0f;
        f32x16 A;
#pragma unroll
        for (int r = 0; r < 16; ++r) A[r] = 0.0f;
#pragma unroll
        for (int ww = 0; ww < 4; ++ww) {
            float scw = __expf(m_sh[ww * 64 + lane] - mstar);
            lstar += l_sh[ww * 64 + lane] * scw;
            const float4* src = (const float4*)&mergeF[((size_t)(ww * 2 + chalf) * 64 + lane) * 16];
#pragma unroll
            for (int r4 = 0; r4 < 4; ++r4) {
                float4 v = src[r4];
                A[4*r4+0] = fmaf(scw, v.x, A[4*r4+0]);
                A[4*r4+1] = fmaf(scw, v.y, A[4*r4+1]);
                A[4*r4+2] = fmaf(scw, v.z, A[4*r4+2]);
                A[4*r4+3] = fmaf(scw, v.w, A[4*r4+3]);
            }
        }
        const float inv = 1.0f / lstar;
        const float g = gamma[0];
#pragma unroll
        for (int r = 0; r < 16; ++r) {
            int c = chalf * 32 + (r & 3) + 8 * (r >> 2) + 4 * h;
            size_t idx = ((size_t)b * C_DIM + c) * NVOX + m0 + l31;
            out[idx] = g * (A[r] * inv) + x[idx];
        }
    }
}

// ---------------------------------------------------------------------------
extern "C" void kernel_launch(void* const* d_in, const int* in_sizes, int n_in,
                              void* d_out, int out_size, void* d_ws, size_t ws_size,
                              hipStream_t stream) {
    const float* x     = (const float*)d_in[0];
    const float* wq    = (const float*)d_in[1];
    const float* bq    = (const float*)d_in[2];
    const float* wk    = (const float*)d_in[3];
    const float* bk    = (const float*)d_in[4];
    const float* wv    = (const float*)d_in[5];
    const float* bv    = (const float*)d_in[6];
    const float* gamma = (const float*)d_in[7];
    float* out = (float*)d_out;

    unsigned short* qws = (unsigned short*)d_ws;            // [16000][16]
    unsigned short* kws = qws + (size_t)BATCH * NVOX * 16;  // [16000][8]
    unsigned short* vws = kws + (size_t)BATCH * NVOX * 8;   // [2][64][8000]

    qkv_kernel<<<QTILES, 256, 0, stream>>>(
        x, wq, bq, wk, bk, wv, bv, qws, kws, vws);

    attn_kernel<<<BATCH * QTILES, 256, 0, stream>>>(
        qws, kws, vws, x, gamma, out);
}

// Round 4
// 142.702 us; speedup vs baseline: 1.8554x; 1.8554x over previous
//
#include <hip/hip_runtime.h>
#include <math.h>

#define C_DIM  64
#define BATCH  2
#define NVOX   8000
#define MT     32            // queries per block
#define KT     64            // keys per tile
#define NTILES 125
#define QTILES 250
#define PSTRIDE 72           // pT row stride (u16), 144 B = 16B-aligned
#define WSTRIDE 72           // W LDS row stride (u16)

typedef float  f32x16 __attribute__((ext_vector_type(16)));
typedef __bf16 bf16x8 __attribute__((ext_vector_type(8)));
typedef unsigned short u16x8 __attribute__((ext_vector_type(8)));

__device__ __forceinline__ unsigned short f2bf(float f) {
    return __builtin_bit_cast(unsigned short, (__bf16)f);
}

// ---------------------------------------------------------------------------
// Kernel 1: projection GEMM via MFMA, hi/lo split bf16 (error ~1e-5 rel).
//   out[96(o),16000(n)] = W[96,64] * X[64,16000], o: 0-7 q, 8-15 k, 16-79 v.
//   500 blocks x 192 thr: block = 32 voxels, wave w = o-tile w (0..2).
// ---------------------------------------------------------------------------
__global__ __launch_bounds__(192) void qkv_kernel(
    const float* __restrict__ x,
    const float* __restrict__ wq, const float* __restrict__ bq,
    const float* __restrict__ wk, const float* __restrict__ bk,
    const float* __restrict__ wv, const float* __restrict__ bv,
    unsigned short* __restrict__ qws, unsigned short* __restrict__ kws,
    unsigned short* __restrict__ vws)
{
    __shared__ unsigned short Whi[96 * WSTRIDE];   // rows 80-95 unwritten (never stored)
    __shared__ unsigned short Wlo[96 * WSTRIDE];
    const int t = threadIdx.x;
    for (int idx = t; idx < 80 * 64; idx += 192) {
        int o = idx >> 6, c = idx & 63;
        float w = (o < 8) ? wq[o * 64 + c]
                : (o < 16) ? wk[(o - 8) * 64 + c]
                : wv[(o - 16) * 64 + c];
        __bf16 hb = (__bf16)w;
        Whi[o * WSTRIDE + c] = __builtin_bit_cast(unsigned short, hb);
        Wlo[o * WSTRIDE + c] = f2bf(w - (float)hb);
    }
    __syncthreads();

    const int lane = t & 63;
    const int ot   = t >> 6;                 // o-tile 0..2
    const int l31  = lane & 31;
    const int h    = lane >> 5;
    const int blk  = blockIdx.x;
    const int b    = blk / 250;
    const int n0   = (blk % 250) * 32;
    const int n    = n0 + l31;
    const int vox  = b * NVOX + n;

    // B-frags: X[c][n] hi/lo, 4 k-chunks of 16; lane (l31=n, h): c = cc*16+8h+j
    bf16x8 Bhi[4], Blo[4];
    const float* xb = x + (size_t)b * 64 * NVOX + n;
#pragma unroll
    for (int cc = 0; cc < 4; ++cc) {
        unsigned short bh[8], bl[8];
#pragma unroll
        for (int j = 0; j < 8; ++j) {
            float xf = xb[(size_t)(cc * 16 + 8 * h + j) * NVOX];   // coalesced over l31
            __bf16 xh = (__bf16)xf;
            bh[j] = __builtin_bit_cast(unsigned short, xh);
            bl[j] = f2bf(xf - (float)xh);
        }
        Bhi[cc] = __builtin_bit_cast(bf16x8, *(u16x8*)bh);
        Blo[cc] = __builtin_bit_cast(bf16x8, *(u16x8*)bl);
    }

    f32x16 acc;
#pragma unroll
    for (int r = 0; r < 16; ++r) acc[r] = 0.0f;
#pragma unroll
    for (int cc = 0; cc < 4; ++cc) {
        const int wo = (ot * 32 + l31) * WSTRIDE + cc * 16 + 8 * h;
        bf16x8 Ah = __builtin_bit_cast(bf16x8, *(const u16x8*)&Whi[wo]);
        bf16x8 Al = __builtin_bit_cast(bf16x8, *(const u16x8*)&Wlo[wo]);
        acc = __builtin_amdgcn_mfma_f32_32x32x16_bf16(Ah, Bhi[cc], acc, 0, 0, 0);
        acc = __builtin_amdgcn_mfma_f32_32x32x16_bf16(Al, Bhi[cc], acc, 0, 0, 0);
        acc = __builtin_amdgcn_mfma_f32_32x32x16_bf16(Ah, Blo[cc], acc, 0, 0, 0);
    }

    // store: C-layout lane holds (o = ot*32 + (r&3)+8*(r>>2)+4h, n = l31)
#pragma unroll
    for (int r = 0; r < 16; ++r) {
        int o = ot * 32 + (r & 3) + 8 * (r >> 2) + 4 * h;
        if (o >= 80) continue;               // padded rows (ot==2 upper half)
        float bias = (o < 8) ? bq[o] : (o < 16) ? bk[o - 8] : bv[o - 16];
        float v = acc[r] + bias;
        if (o < 8) {                         // q: split hi/lo
            __bf16 hb = (__bf16)v;
            qws[(size_t)vox * 16 + o]     = __builtin_bit_cast(unsigned short, hb);
            qws[(size_t)vox * 16 + 8 + o] = f2bf(v - (float)hb);
        } else if (o < 16) {
            kws[(size_t)vox * 8 + (o - 8)] = f2bf(v);
        } else {
            vws[((size_t)b * 64 + (o - 16)) * NVOX + n] = f2bf(v);
        }
    }
}

// ---------------------------------------------------------------------------
// Kernel 2: flash attention, ZERO barriers in main loop.
//   500 blocks x 256 thr; wave w owns tiles T = w+4S (private m,l,acc,pT).
//   V and K fragments load DIRECTLY from global (L2-resident) into regs —
//   no LDS staging, no cross-wave sync. pT round-trip is wave-private.
// ---------------------------------------------------------------------------
__global__ __launch_bounds__(256) void attn_kernel(
    const unsigned short* __restrict__ qws, const unsigned short* __restrict__ kws,
    const unsigned short* __restrict__ vws, const float* __restrict__ x,
    const float* __restrict__ gamma, float* __restrict__ out)
{
    __shared__ __align__(16) unsigned char smem[32768 + 2048];
    unsigned short* pT  = (unsigned short*)smem;          // [4][32][72] = 18432 B
    float* mergeF = (float*)smem;                         // [4][2][64][16] = 32768 B (after barrier)
    float* m_sh = (float*)(smem + 32768);                 // [4][64]
    float* l_sh = m_sh + 256;                             // [4][64]

    const int blk  = blockIdx.x;
    const int b    = blk / QTILES;
    const int m0   = (blk % QTILES) * MT;
    const int t    = threadIdx.x;
    const int lane = t & 63;
    const int w    = t >> 6;
    const int l31  = lane & 31;
    const int h    = lane >> 5;

    // Q B-frag: col = query l31; h=0 carries qhi (k-dims 0-7), h=1 qlo (8-15)
    const bf16x8 qf = __builtin_bit_cast(bf16x8,
        *(const u16x8*)(qws + (size_t)(b * NVOX + m0 + l31) * 16 + h * 8));

    const unsigned short* ksrc = kws + (size_t)b * NVOX * 8;
    // V A-frag base: lane (l31,h) reads V[c = ch*32+l31][key n0+16*s2+8h ..+8]
    const unsigned short* vb0 = vws + ((size_t)b * 64 + l31) * NVOX + 8 * h;
    const size_t vch = (size_t)32 * NVOX;

    float m_run = -1e30f, l_run = 0.0f;
    f32x16 acc0, acc1, zro;
#pragma unroll
    for (int r = 0; r < 16; ++r) { acc0[r] = 0.0f; acc1[r] = 0.0f; zro[r] = 0.0f; }

    unsigned short* prow = pT + (size_t)(w * MT + l31) * PSTRIDE;

    // prefetch K frags for first tile (T = w); A-frag dup across h -> (qhi+qlo)*k
    bf16x8 kf0 = __builtin_bit_cast(bf16x8, *(const u16x8*)(ksrc + (size_t)(w * KT + l31) * 8));
    bf16x8 kf1 = __builtin_bit_cast(bf16x8, *(const u16x8*)(ksrc + (size_t)(w * KT + 32 + l31) * 8));

    for (int S = 0; S < 32; ++S) {
        const int T = w + 4 * S;
        if (T < NTILES) {
            const int n0 = T * KT;

            // ---- issue V A-frag loads early (latency hidden by QK+softmax)
            uint4 va[8];
#pragma unroll
            for (int s2 = 0; s2 < 4; ++s2) {
                va[s2 * 2 + 0] = *(const uint4*)(vb0 + n0 + s2 * 16);
                va[s2 * 2 + 1] = *(const uint4*)(vb0 + vch + n0 + s2 * 16);
            }

            // ---- QK energies: E C-layout col=q (l31), row=key (r&3)+8(r>>2)+4h
            f32x16 E0 = __builtin_amdgcn_mfma_f32_32x32x16_bf16(kf0, qf, zro, 0, 0, 0);
            f32x16 E1 = __builtin_amdgcn_mfma_f32_32x32x16_bf16(kf1, qf, zro, 0, 0, 0);

            // ---- prefetch K for next tile
            const int Tn = T + 4;
            if (Tn < NTILES) {
                kf0 = __builtin_bit_cast(bf16x8, *(const u16x8*)(ksrc + (size_t)(Tn * KT + l31) * 8));
                kf1 = __builtin_bit_cast(bf16x8, *(const u16x8*)(ksrc + (size_t)(Tn * KT + 32 + l31) * 8));
            }

            // ---- online softmax (reg-resident; one shfl across h-halves)
            float tm = E0[0];
#pragma unroll
            for (int r = 1; r < 16; ++r) tm = fmaxf(tm, E0[r]);
#pragma unroll
            for (int r = 0; r < 16; ++r) tm = fmaxf(tm, E1[r]);
            tm = fmaxf(tm, __shfl_xor(tm, 32, 64));
            const float mnew  = fmaxf(m_run, tm);
            const float alpha = __expf(m_run - mnew);
            float s = 0.0f;
#pragma unroll
            for (int r = 0; r < 16; ++r) { E0[r] = __expf(E0[r] - mnew); s += E0[r]; }
#pragma unroll
            for (int r = 0; r < 16; ++r) { E1[r] = __expf(E1[r] - mnew); s += E1[r]; }
            s += __shfl_xor(s, 32, 64);
            m_run = mnew;
            l_run = l_run * alpha + s;

            // ---- P -> wave-private pT ([q][key] bf16); keys 8g+4h..+3 per reg grp
#pragma unroll
            for (int g4 = 0; g4 < 4; ++g4) {
                ushort4 pk;
                pk.x = f2bf(E0[4 * g4 + 0]); pk.y = f2bf(E0[4 * g4 + 1]);
                pk.z = f2bf(E0[4 * g4 + 2]); pk.w = f2bf(E0[4 * g4 + 3]);
                *(ushort4*)(prow + g4 * 8 + 4 * h) = pk;
            }
#pragma unroll
            for (int g4 = 0; g4 < 4; ++g4) {
                ushort4 pk;
                pk.x = f2bf(E1[4 * g4 + 0]); pk.y = f2bf(E1[4 * g4 + 1]);
                pk.z = f2bf(E1[4 * g4 + 2]); pk.w = f2bf(E1[4 * g4 + 3]);
                *(ushort4*)(prow + 32 + g4 * 8 + 4 * h) = pk;
            }

            // ---- rescale acc (cols = this lane's query -> scalar alpha)
#pragma unroll
            for (int r = 0; r < 16; ++r) { acc0[r] *= alpha; acc1[r] *= alpha; }

            // ---- PV: A = V frags (regs, direct-from-global), B = P from pT
#pragma unroll
            for (int s2 = 0; s2 < 4; ++s2) {
                bf16x8 pf = __builtin_bit_cast(bf16x8,
                    *(const u16x8*)(prow + s2 * 16 + h * 8));
                acc0 = __builtin_amdgcn_mfma_f32_32x32x16_bf16(
                    __builtin_bit_cast(bf16x8, va[s2 * 2 + 0]), pf, acc0, 0, 0, 0);
                acc1 = __builtin_amdgcn_mfma_f32_32x32x16_bf16(
                    __builtin_bit_cast(bf16x8, va[s2 * 2 + 1]), pf, acc1, 0, 0, 0);
            }
        }
    }

    // ---- flash-decode merge across the 4 waves ----
    m_sh[w * 64 + lane] = m_run;
    l_sh[w * 64 + lane] = l_run;
    __syncthreads();                          // all main-loop pT use complete
#pragma unroll
    for (int r4 = 0; r4 < 4; ++r4) {
        float4 a0 = make_float4(acc0[4*r4+0], acc0[4*r4+1], acc0[4*r4+2], acc0[4*r4+3]);
        float4 a1 = make_float4(acc1[4*r4+0], acc1[4*r4+1], acc1[4*r4+2], acc1[4*r4+3]);
        *(float4*)&mergeF[((size_t)(w * 2 + 0) * 64 + lane) * 16 + 4 * r4] = a0;
        *(float4*)&mergeF[((size_t)(w * 2 + 1) * 64 + lane) * 16 + 4 * r4] = a1;
    }
    __syncthreads();

    if (w < 2) {
        const int chalf = w;
        float mstar = m_sh[lane];
#pragma unroll
        for (int ww = 1; ww < 4; ++ww) mstar = fmaxf(mstar, m_sh[ww * 64 + lane]);
        float lstar = 0.0f;
        f32x16 A;
#pragma unroll
        for (int r = 0; r < 16; ++r) A[r] = 0.0f;
#pragma unroll
        for (int ww = 0; ww < 4; ++ww) {
            float scw = __expf(m_sh[ww * 64 + lane] - mstar);
            lstar += l_sh[ww * 64 + lane] * scw;
            const float4* src = (const float4*)&mergeF[((size_t)(ww * 2 + chalf) * 64 + lane) * 16];
#pragma unroll
            for (int r4 = 0; r4 < 4; ++r4) {
                float4 v = src[r4];
                A[4*r4+0] = fmaf(scw, v.x, A[4*r4+0]);
                A[4*r4+1] = fmaf(scw, v.y, A[4*r4+1]);
                A[4*r4+2] = fmaf(scw, v.z, A[4*r4+2]);
                A[4*r4+3] = fmaf(scw, v.w, A[4*r4+3]);
            }
        }
        const float inv = 1.0f / lstar;
        const float g = gamma[0];
#pragma unroll
        for (int r = 0; r < 16; ++r) {
            int c = chalf * 32 + (r & 3) + 8 * (r >> 2) + 4 * h;
            size_t idx = ((size_t)b * C_DIM + c) * NVOX + m0 + l31;
            out[idx] = g * (A[r] * inv) + x[idx];
        }
    }
}

// ---------------------------------------------------------------------------
extern "C" void kernel_launch(void* const* d_in, const int* in_sizes, int n_in,
                              void* d_out, int out_size, void* d_ws, size_t ws_size,
                              hipStream_t stream) {
    const float* x     = (const float*)d_in[0];
    const float* wq    = (const float*)d_in[1];
    const float* bq    = (const float*)d_in[2];
    const float* wk    = (const float*)d_in[3];
    const float* bk    = (const float*)d_in[4];
    const float* wv    = (const float*)d_in[5];
    const float* bv    = (const float*)d_in[6];
    const float* gamma = (const float*)d_in[7];
    float* out = (float*)d_out;

    unsigned short* qws = (unsigned short*)d_ws;            // [16000][16] hi|lo
    unsigned short* kws = qws + (size_t)BATCH * NVOX * 16;  // [16000][8]
    unsigned short* vws = kws + (size_t)BATCH * NVOX * 8;   // [2][64][8000]

    qkv_kernel<<<500, 192, 0, stream>>>(
        x, wq, bq, wk, bk, wv, bv, qws, kws, vws);

    attn_kernel<<<BATCH * QTILES, 256, 0, stream>>>(
        qws, kws, vws, x, gamma, out);
}